// Round 8
// baseline (1038.859 us; speedup 1.0000x reference)
//
#include <hip/hip_runtime.h>
#include <hip/hip_bf16.h>

#define NT 512          // fused phaseA block size (8 waves)
#define NW (NT / 64)    // waves per block
#define NNODES 4096
#define ECAP 65536      // max arcs after iteration-1 symmetrization (E0 <= 32768)

// ---------------- grid-parallel 2MB bitmap zero ----------------
__global__ __launch_bounds__(256)
void zeroBM(int4* __restrict__ bm) {
    bm[(size_t)blockIdx.x * 256 + threadIdx.x] = make_int4(0, 0, 0, 0);
}

// ---------------- block-wide exclusive scan over NT values (NW waves) ----------------
__device__ __forceinline__ int blockScanExcl(int v, int* s_w, int* total) {
    const int tid  = threadIdx.x;
    const int lane = tid & 63;
    const int wv   = tid >> 6;
    int x = v;
#pragma unroll
    for (int off = 1; off < 64; off <<= 1) {
        int t = __shfl_up(x, off, 64);
        if (lane >= off) x += t;
    }
    if (lane == 63) s_w[wv] = x;
    __syncthreads();
    if (tid < 16) {
        int y = (tid < NW) ? s_w[tid] : 0;   // unused slots contribute 0
#pragma unroll
        for (int off = 1; off < 16; off <<= 1) {
            int t = __shfl_up(y, off, 16);
            if (tid >= off) y += t;
        }
        s_w[tid] = y;
    }
    __syncthreads();
    int base = wv ? s_w[wv - 1] : 0;
    int tot  = s_w[15];
    __syncthreads();   // protect s_w reuse
    *total = tot;
    return base + x - v;   // exclusive prefix
}

// ================= Fused Phase A = A1 (preamble) + A2 (wave-0 main loop) + A3 =================
// s_bc slots: 0=hub0 2=cnt0 3=K 4=orderBase(legacy) 5=appendBase 7=maxdeg 9=not64 10=A3 base
__global__ __launch_bounds__(NT, 1)
void phaseA(const int* __restrict__ ei, int E0,
            int* __restrict__ U, int* __restrict__ V,
            unsigned int* __restrict__ BM,
            int* __restrict__ NBR, int* __restrict__ OTH,
            int* __restrict__ SEL, int* __restrict__ CNTS,
            int* __restrict__ NST, int* __restrict__ FIL, int* __restrict__ SC,
            int* __restrict__ TMP, float* __restrict__ out)
{
    // -------- LDS (no cross-phase aliasing except documented s_degcnt) --------
    __shared__ unsigned short s_ord[NNODES];      // sort output; order slot -> node
    __shared__ unsigned short s_pos[NNODES];      // node -> order slot
    __shared__ unsigned short s_so[NNODES];       // selection order of hubs (A2)
    __shared__ unsigned char  s_rank[NNODES];     // counting-sort within-group rank
    __shared__ unsigned int   s_visbits[NNODES / 32]; // visited bit per order slot
    __shared__ unsigned int   s_hb[NNODES / 32];  // iter-0 hub-neighbor bitmap
    __shared__ unsigned int   s_meta[NNODES];     // A2 fused label/slot/sel; A3 lab
    __shared__ int s_mat[64][65];                 // counting-sort matrix
    __shared__ int s_roff[NNODES];                // CSR (A1 build -> A2 use)
    __shared__ int s_rend[NNODES];
    __shared__ int s_stamp[NNODES];               // A2 dedup scratch -> rank (A3 rnk)
    __shared__ int s_degcnt[NNODES];              // A1 degrees -> iter-0 stage -> A2 s_cnt
    __shared__ int s_w[16];
    __shared__ int s_bc[16];

    const int tid = threadIdx.x;

    for (int i = tid; i < NNODES; i += NT) s_degcnt[i] = 0;
    for (int i = tid; i < NNODES / 32; i += NT) { s_hb[i] = 0u; s_visbits[i] = 0u; }
    if (tid < 16) s_bc[tid] = 0;
    __syncthreads();

    // ---- detect int64 vs int32 edge buffer ----
    for (int i = tid; i < E0; i += NT)
        if (ei[2 * i + 1] != 0) s_bc[9] = 1;
    __syncthreads();
    const int is64 = !s_bc[9];

    // ---- copy edges + degree histogram (I+O) ----
    for (int e = tid; e < E0; e += NT) {
        int uu = ei[is64 ? 2 * e : e];
        int vv = ei[is64 ? 2 * (E0 + e) : (E0 + e)];
        U[e] = uu; V[e] = vv;
        atomicAdd(&s_degcnt[uu], 1);
        atomicAdd(&s_degcnt[vv], 1);
    }
    __syncthreads();
    for (int n = tid; n < NNODES; n += NT) atomicMax(&s_bc[7], s_degcnt[n]);
    __syncthreads();
    const int maxd = s_bc[7];

    // ---- stable argsort by descending degree ----
    if (maxd < 64) {
        // counting sort, ~5 barriers
        const int wv = tid >> 6, lane = tid & 63;
        const unsigned long long wltm = (1ull << lane) - 1ull;
        for (int g = wv; g < 64; g += NW) {
            int n = g * 64 + lane;
            int d = s_degcnt[n];
            int rk = 0;
            for (int dd = 0; dd < 64; ++dd) {
                unsigned long long bal = __ballot(d == dd);
                if (lane == 0) s_mat[dd][g] = __popcll(bal);
                if (d == dd) rk = __popcll(bal & wltm);
            }
            s_rank[n] = (unsigned char)rk;
        }
        __syncthreads();
        if (tid < 64) {                      // per-degree prefix across the 64 id-groups
            int run = 0;
            for (int g = 0; g < 64; ++g) { int t = s_mat[tid][g]; s_mat[tid][g] = run; run += t; }
            s_mat[tid][64] = run;            // total per degree
        }
        __syncthreads();
        if (tid < 64) {                      // descending-degree exclusive base
            int x = s_mat[tid][64];
#pragma unroll
            for (int off = 1; off < 64; off <<= 1) {
                int t = __shfl_up(x, off, 64);
                if (tid >= off) x += t;
            }
            int T = __shfl(x, 63, 64);
            s_mat[tid][64] = T - x;          // sum of bins with degree > tid
        }
        __syncthreads();
        for (int g = wv; g < 64; g += NW) {
            int n = g * 64 + lane;
            int d = s_degcnt[n];
            int pos = s_mat[d][64] + s_mat[d][g] + (int)s_rank[n];
            s_ord[pos] = (unsigned short)n;
        }
        __syncthreads();
    } else {
        // legacy fallback (exact, slow): one scan round per degree value, 8 nodes/thread
        for (int d = maxd; d >= 0; --d) {
            const int n0 = tid * 8;
            int f[8], cnt = 0;
#pragma unroll
            for (int q = 0; q < 8; ++q) { f[q] = (s_degcnt[n0 + q] == d); cnt += f[q]; }
            int tot;
            int off = blockScanExcl(cnt, s_w, &tot);
            int idx = s_bc[4] + off;
#pragma unroll
            for (int q = 0; q < 8; ++q)
                if (f[q]) s_ord[idx++] = (unsigned short)(n0 + q);
            __syncthreads();
            if (tid == 0) s_bc[4] += tot;
            __syncthreads();
        }
    }

    // ---- inverse permutation ----
    for (int i = tid; i < NNODES; i += NT) s_pos[s_ord[i]] = (unsigned short)i;
    __syncthreads();

    // ---- iteration 0 (full-array scans, eager relabel) ----
    if (tid == 0) {
        s_bc[0] = (int)s_ord[0];
        atomicOr(&s_visbits[0], 1u);          // slot 0 = hub0
    }
    __syncthreads();
    {
        const int node = s_bc[0];
        for (int e = tid; e < E0; e += NT) {
            int uu = U[e], vv = V[e];
            if (uu == node) {
                int w = vv; unsigned m = 1u << (w & 31);
                unsigned old = atomicOr(&s_hb[w >> 5], m);
                if (!(old & m)) {
                    int i = atomicAdd(&s_bc[2], 1);
                    s_degcnt[i] = w;          // stage (degrees dead after sort)
                    int sl = (int)s_pos[w];
                    atomicOr(&s_visbits[sl >> 5], 1u << (sl & 31));
                }
            }
            if (vv == node) {
                int w = uu; unsigned m = 1u << (w & 31);
                unsigned old = atomicOr(&s_hb[w >> 5], m);
                if (!(old & m)) {
                    int i = atomicAdd(&s_bc[2], 1);
                    s_degcnt[i] = w;
                    int sl = (int)s_pos[w];
                    atomicOr(&s_visbits[sl >> 5], 1u << (sl & 31));
                }
            }
        }
        __syncthreads();
        // eager relabel Hn = H \ {node} (U/V frozen afterwards)
        for (int e = tid; e < E0; e += NT) {
            int uu = U[e];
            if (uu != node && ((s_hb[uu >> 5] >> (uu & 31)) & 1)) U[e] = node;
            int vv = V[e];
            if (vv != node && ((s_hb[vv >> 5] >> (vv & 31)) & 1)) V[e] = node;
        }
        __syncthreads();
    }

    // ---- symmetry append (BM pre-zeroed by zeroBM) ----
    for (int e = tid; e < E0; e += NT) {
        int uu = U[e], vv = V[e];
        if (uu != vv) {
            unsigned code = ((unsigned)uu << 12) | (unsigned)vv;
            atomicOr(&BM[code >> 5], 1u << (code & 31));
        }
    }
    __syncthreads();
    for (int t0 = 0; t0 < E0; t0 += NT * 32) {
        unsigned fm = 0u;
        const int base = t0 + tid * 32;
        for (int j = 0; j < 32; ++j) {
            int e = base + j;
            if (e < E0) {
                int uu = U[e], vv = V[e];
                if (uu != vv) {
                    unsigned rc = ((unsigned)vv << 12) | (unsigned)uu;
                    unsigned old = atomicOr(&BM[rc >> 5], 0u);   // L2 read
                    if (!((old >> (rc & 31)) & 1u)) fm |= (1u << j);
                }
            }
        }
        int tot;
        int off = blockScanExcl(__popc(fm), s_w, &tot);
        int r = s_bc[5] + off;
        unsigned m = fm;
        while (m) {
            int j = __ffs((int)m) - 1; m &= m - 1;
            int e = base + j;
            U[E0 + r] = V[e]; V[E0 + r] = U[e];
            ++r;
        }
        __syncthreads();
        if (tid == 0) s_bc[5] += tot;
        __syncthreads();
    }
    const int E1 = E0 + s_bc[5];

    // ---- build static CSR, OUT-endpoint only (arc set symmetric after append) ----
    for (int n = tid; n < NNODES; n += NT) s_roff[n] = 0;
    __syncthreads();
    for (int e = tid; e < E1; e += NT) {
        int uu = U[e], vv = V[e];
        if (uu != vv) atomicAdd(&s_roff[uu], 1);
    }
    __syncthreads();
    {   // prefix over 4096 counts, 8 per thread
        const int n0 = tid * 8;
        int c[8], s = 0;
#pragma unroll
        for (int q = 0; q < 8; ++q) { c[q] = s_roff[n0 + q]; s += c[q]; }
        int tot;
        int off = blockScanExcl(s, s_w, &tot);
        int st = off;
#pragma unroll
        for (int q = 0; q < 8; ++q) {
            s_roff[n0 + q] = st; s_rend[n0 + q] = st; st += c[q];
        }
    }
    __syncthreads();
    for (int e = tid; e < E1; e += NT) {
        int uu = U[e], vv = V[e];
        if (uu != vv) {
            int p = atomicAdd(&s_rend[uu], 1);
            OTH[p] = vv;
        }
    }
    __syncthreads();
    // ---- flush iter-0 staged H into global NBR (before s_degcnt becomes s_cnt) ----
    const int cnt0 = s_bc[2];
    for (int i = tid; i < cnt0; i += NT) NBR[i] = s_degcnt[i];
    __syncthreads();

    // ---- A2 init (all threads) ----
    for (int i = tid; i < NNODES; i += NT) {
        int nd = (int)s_ord[i];
        s_meta[nd] = ((unsigned)i << 16) | (unsigned)nd;   // slot | id, unselected
        s_stamp[i] = 0;
        s_degcnt[i] = 0;                                   // now A2 s_cnt
    }
    __syncthreads();
    if (tid == 0) {
        int hub0 = s_bc[0];
        s_meta[hub0] = (unsigned)hub0 | 0x8000u;           // slot 0 | id | selected
        s_so[0] = (unsigned short)hub0;
        s_degcnt[0] = cnt0;
    }
    __syncthreads();

    // ================= A2 main loop: WAVE 0 ONLY (round-5 quad core) =================
    if (tid < 64) {
        const int ln = tid;
        const unsigned long long ltm = (1ull << ln) - 1ull;
        volatile int* vstamp = s_stamp;

        int nc = cnt0;
        int k = 1;

        unsigned lo = 0u, hi = 0u;
        auto extract = [&]() -> int {
            unsigned long long b = __ballot(lo != 0u);
            if (b) {
                int sl = __ffsll((long long)b) - 1;
                unsigned ww = __shfl(lo, sl, 64);
                if (ln == sl) lo &= lo - 1;
                return sl * 32 + (__ffs((int)ww) - 1);
            }
            b = __ballot(hi != 0u);
            if (b) {
                int sl = __ffsll((long long)b) - 1;
                unsigned ww = __shfl(hi, sl, 64);
                if (ln == sl) hi &= hi - 1;
                return 2048 + sl * 32 + (__ffs((int)ww) - 1);
            }
            return -1;
        };

        auto commitNew = [&](unsigned g, int w, bool nw, unsigned long long bal,
                             unsigned relv) {
            if (nw) {
                NBR[nc + __popcll(bal & ltm)] = w;       // fire-and-forget
                int slot = (int)(g >> 16);
                atomicOr(&s_visbits[slot >> 5], 1u << (slot & 31));
                if (!(g & 0x8000u)) s_meta[w] = relv;
            }
            nc += __popcll(bal);
        };

        auto procFast = [&](int hub, int hslot, int o, unsigned g) {
            const unsigned relv = ((unsigned)hslot << 16) | (unsigned)hub | 0x8000u;
            int w = (o >= 0) ? (int)(g & 0x7FFFu) : hub;
            bool valid = (o >= 0) && (w != hub);
            if (valid) vstamp[w] = ln;                   // plain store (one winner/addr)
            int r = valid ? vstamp[w] : -1;              // in-order read-back
            bool nw = valid && (r == ln);
            unsigned long long bal = __ballot(nw);
            commitNew(g, w, nw, bal, relv);
        };

        auto procSlow = [&](int hub, int hslot, int rb, int re, int o0) {
            const unsigned relv = ((unsigned)hslot << 16) | (unsigned)hub | 0x8000u;
            const int key = k << 6;                      // lane-ids < 64 <= key
            int o = o0;
            for (int s0 = rb; s0 < re; s0 += 64) {
                unsigned g = (o >= 0) ? s_meta[o] : 0u;
                int w = (o >= 0) ? (int)(g & 0x7FFFu) : hub;
                bool cnd = (w != hub);
                int old = key;
                if (cnd) old = atomicMax(&s_stamp[w], key);
                bool nw = cnd && (old < key);
                unsigned long long bal = __ballot(nw);
                commitNew(g, w, nw, bal, relv);
                int s1 = s0 + 64;
                o = (s1 + ln < re) ? OTH[s1 + ln] : -1;
            }
        };

        for (;;) {
            lo = ~s_visbits[ln]; hi = ~s_visbits[ln + 64];
            int sl0 = extract();
            if (sl0 < 0) break;
            int sl1 = extract(), sl2 = -1, sl3 = -1;
            if (sl1 >= 0) { sl2 = extract(); if (sl2 >= 0) sl3 = extract(); }

            int c0 = (int)s_ord[sl0];
            int c1 = (sl1 >= 0) ? (int)s_ord[sl1] : -1;
            int c2 = (sl2 >= 0) ? (int)s_ord[sl2] : -1;
            int c3 = (sl3 >= 0) ? (int)s_ord[sl3] : -1;

            {   // pre-mark candidates (monotone extraction)
                int ms = (ln == 0) ? sl0 : (ln == 1) ? sl1 : (ln == 2) ? sl2 : sl3;
                if (ln < 4 && ms >= 0) atomicOr(&s_visbits[ms >> 5], 1u << (ms & 31));
            }

            int rb0 = s_roff[c0], re0 = s_rend[c0];
            int rb1 = 0, re1 = 0, rb2 = 0, re2 = 0, rb3 = 0, re3 = 0;
            if (c1 >= 0) { rb1 = s_roff[c1]; re1 = s_rend[c1]; }
            if (c2 >= 0) { rb2 = s_roff[c2]; re2 = s_rend[c2]; }
            if (c3 >= 0) { rb3 = s_roff[c3]; re3 = s_rend[c3]; }
            int v0 = (rb0 + ln < re0) ? OTH[rb0 + ln] : -1;
            int v1 = (c1 >= 0 && rb1 + ln < re1) ? OTH[rb1 + ln] : -1;
            int v2 = (c2 >= 0 && rb2 + ln < re2) ? OTH[rb2 + ln] : -1;
            int v3 = (c3 >= 0 && rb3 + ln < re3) ? OTH[rb3 + ln] : -1;

            // ---- proc c0 (never absorbed: unvisited at snapshot) ----
            if (ln == 0) {
                s_meta[c0] = ((unsigned)sl0 << 16) | (unsigned)c0 | 0x8000u;
                s_so[k] = (unsigned short)c0;
            }
            {
                unsigned g0 = (v0 >= 0) ? s_meta[v0] : 0u;
                int begin = nc;
                if (re0 - rb0 <= 64) procFast(c0, sl0, v0, g0);
                else                 procSlow(c0, sl0, rb0, re0, v0);
                if (ln == 0) s_degcnt[k] = nc - begin;
                k++;
            }
            // ---- c1..c3: absorption check fused with row gather ----
            if (c1 >= 0) {
                unsigned m1 = s_meta[c1];
                unsigned g1 = (v1 >= 0) ? s_meta[v1] : 0u;
                if ((int)(m1 & 0x7FFFu) == c1) {
                    if (ln == 0) {
                        s_meta[c1] = ((unsigned)sl1 << 16) | (unsigned)c1 | 0x8000u;
                        s_so[k] = (unsigned short)c1;
                    }
                    int begin = nc;
                    if (re1 - rb1 <= 64) procFast(c1, sl1, v1, g1);
                    else                 procSlow(c1, sl1, rb1, re1, v1);
                    if (ln == 0) s_degcnt[k] = nc - begin;
                    k++;
                }
            }
            if (c2 >= 0) {
                unsigned m2 = s_meta[c2];
                unsigned g2 = (v2 >= 0) ? s_meta[v2] : 0u;
                if ((int)(m2 & 0x7FFFu) == c2) {
                    if (ln == 0) {
                        s_meta[c2] = ((unsigned)sl2 << 16) | (unsigned)c2 | 0x8000u;
                        s_so[k] = (unsigned short)c2;
                    }
                    int begin = nc;
                    if (re2 - rb2 <= 64) procFast(c2, sl2, v2, g2);
                    else                 procSlow(c2, sl2, rb2, re2, v2);
                    if (ln == 0) s_degcnt[k] = nc - begin;
                    k++;
                }
            }
            if (c3 >= 0) {
                unsigned m3 = s_meta[c3];
                unsigned g3 = (v3 >= 0) ? s_meta[v3] : 0u;
                if ((int)(m3 & 0x7FFFu) == c3) {
                    if (ln == 0) {
                        s_meta[c3] = ((unsigned)sl3 << 16) | (unsigned)c3 | 0x8000u;
                        s_so[k] = (unsigned short)c3;
                    }
                    int begin = nc;
                    if (re3 - rb3 <= 64) procFast(c3, sl3, v3, g3);
                    else                 procSlow(c3, sl3, rb3, re3, v3);
                    if (ln == 0) s_degcnt[k] = nc - begin;
                    k++;
                }
            }
        }
        const int K = k;

        // ---- rank of selected nodes; overwrite s_stamp ----
        {
            int base = 0;
            for (int c = 0; c < NNODES / 64; ++c) {
                int n = c * 64 + ln;
                unsigned mv = s_meta[n];
                int f = ((mv & 0x8000u) != 0u) && ((int)(mv & 0x7FFFu) == n);
                unsigned long long b = __ballot(f);
                s_stamp[n] = base + __popcll(b & ltm);
                base += __popcll(b);
            }
        }
        // ---- SEL / CNTS / NST ----
        {
            int nb = 0;
            for (int c = 0; c * 64 < K; ++c) {
                int i = c * 64 + ln;
                int cv = (i < K) ? s_degcnt[i] : 0;
                int x = cv;
#pragma unroll
                for (int off = 1; off < 64; off <<= 1) {
                    int t = __shfl_up(x, off, 64);
                    if (ln >= off) x += t;
                }
                if (i < K) { NST[i] = nb + x - cv; CNTS[i] = cv; SEL[i] = (int)s_so[i]; }
                nb += __shfl(x, 63, 64);
            }
        }
        // ---- FIL forward-fill ----
        {
            int carry = 0;
            for (int c = 0; c * 64 < K; ++c) {
                int i = c * 64 + ln;
                int f = (i < K) && (s_degcnt[i] > 0);
                unsigned long long b = __ballot(f);
                unsigned long long m = b & ((ln == 63) ? ~0ull : ((1ull << (ln + 1)) - 1ull));
                int fil = m ? (c * 64 + 63 - __clzll(m)) : carry;
                if (i < K) FIL[i] = fil;
                carry = b ? (c * 64 + 63 - __clzll(b)) : carry;
            }
        }
        if (ln == 0) { SC[0] = K; s_bc[3] = K; }
    }
    __syncthreads();

    // ================= A3: final arc compaction + remap (all NT threads) =================
    // lab(x) = s_meta[x] & 0x7FFF ; rnk(r) = s_stamp[r]  — zero staging copies.
    const int K = s_bc[3];
    const size_t obase = (size_t)K * 8192;
    // s_bc[10] == 0 from the top-of-kernel init (A3 running base)

    for (int t0 = 0; t0 < E1; t0 += NT * 64) {
        unsigned long long fm = 0ull;
        const int base = t0 + tid * 64;
        if (base + 64 <= E1) {                   // vectorized int4 loads
            const int4* U4 = (const int4*)(U + base);
            const int4* V4 = (const int4*)(V + base);
#pragma unroll
            for (int q = 0; q < 16; ++q) {
                int4 a = U4[q], b = V4[q];
                int j = q * 4;
                if ((s_meta[a.x] ^ s_meta[b.x]) & 0x7FFFu) fm |= 1ull << j;
                if ((s_meta[a.y] ^ s_meta[b.y]) & 0x7FFFu) fm |= 1ull << (j + 1);
                if ((s_meta[a.z] ^ s_meta[b.z]) & 0x7FFFu) fm |= 1ull << (j + 2);
                if ((s_meta[a.w] ^ s_meta[b.w]) & 0x7FFFu) fm |= 1ull << (j + 3);
            }
        } else {
            for (int j = 0; j < 64; ++j) {
                int e = base + j;
                if (e < E1) {
                    if ((s_meta[U[e]] ^ s_meta[V[e]]) & 0x7FFFu) fm |= 1ull << j;
                }
            }
        }
        int tot;
        int off = blockScanExcl(__popcll(fm), s_w, &tot);
        int r = s_bc[10] + off;
        unsigned long long m = fm;
        while (m) {
            int j = __ffsll((long long)m) - 1; m &= m - 1;
            int e = base + j;
            out[obase + (size_t)r] = (float)s_stamp[(int)(s_meta[U[e]] & 0x7FFFu)];
            TMP[r] = s_stamp[(int)(s_meta[V[e]] & 0x7FFFu)];
            ++r;
        }
        __syncthreads();
        if (tid == 0) s_bc[10] += tot;
        __syncthreads();
    }
    const int Ef = s_bc[10];
    if (tid == 0) SC[1] = Ef;
    for (int r = tid; r < Ef; r += NT)
        out[obase + (size_t)Ef + (size_t)r] = (float)TMP[r];
}

// ---------------- Phase B: END rows (Dv | mean) with fill indirection ----------------
__global__ __launch_bounds__(256, 4)
void phaseB(const float* __restrict__ x,
            const float* __restrict__ W1, const float* __restrict__ W2,
            const float* __restrict__ B1, const float* __restrict__ B2,
            const int* __restrict__ NBR, const int* __restrict__ SEL,
            const int* __restrict__ CNTS, const int* __restrict__ NST,
            const int* __restrict__ FIL, const int* __restrict__ SC,
            float* __restrict__ out)
{
    const int K = SC[0];
    const int k = blockIdx.x;
    if (k >= K) return;
    const int kk   = FIL[k];
    const int node = SEL[kk];
    const int cnt  = CNTS[kk];
    const int st   = NST[kk];
    const int tid  = threadIdx.x;
    const float4* x4 = (const float4*)x;

    float4 acc[4];
#pragma unroll
    for (int j = 0; j < 4; j++) acc[j] = make_float4(0.f, 0.f, 0.f, 0.f);

    for (int r = 0; r < cnt; ++r) {
        const float4* row = x4 + (size_t)NBR[st + r] * 1024;
#pragma unroll
        for (int j = 0; j < 4; j++) {
            float4 t = row[tid + j * 256];
            acc[j].x += t.x; acc[j].y += t.y; acc[j].z += t.z; acc[j].w += t.w;
        }
    }

    const float fc  = (float)cnt;
    const float inv = 1.0f / (float)(cnt > 1 ? cnt : 1);
    const float4* xr = x4 + (size_t)node * 1024;
    float4* o4 = (float4*)(out + (size_t)k * 8192);

#pragma unroll
    for (int j = 0; j < 4; j++) {
        int c = tid + j * 256;
        float4 w1 = ((const float4*)W1)[c], b1 = ((const float4*)B1)[c];
        float4 w2 = ((const float4*)W2)[c], b2 = ((const float4*)B2)[c];
        float4 xv = xr[c];
        float4 pd, pm;
        pd.x = xv.x * w2.x + b2.x;
        pd.y = xv.y * w2.y + b2.y;
        pd.z = xv.z * w2.z + b2.z;
        pd.w = xv.w * w2.w + b2.w;
        pm.x = (acc[j].x * w1.x + fc * b1.x) * inv;
        pm.y = (acc[j].y * w1.y + fc * b1.y) * inv;
        pm.z = (acc[j].z * w1.z + fc * b1.z) * inv;
        pm.w = (acc[j].w * w1.w + fc * b1.w) * inv;
        o4[c] = pd;
        o4[1024 + c] = pm;
    }
}

extern "C" void kernel_launch(void* const* d_in, const int* in_sizes, int n_in,
                              void* d_out, int out_size, void* d_ws, size_t ws_size,
                              hipStream_t stream)
{
    const float* x  = (const float*)d_in[0];
    const int*   ei = (const int*)d_in[1];
    const float* W1 = (const float*)d_in[2];
    const float* W2 = (const float*)d_in[3];
    const float* B1 = (const float*)d_in[4];
    const float* B2 = (const float*)d_in[5];
    const int E0 = in_sizes[1] / 2;

    char* w = (char*)d_ws;
    int* U = (int*)w;                         // [ECAP]
    int* V = U + ECAP;                        // [ECAP]
    unsigned int* BM = (unsigned int*)(V + ECAP);   // 2 MB bitmap (iter-0 only)
    int* OTH = (int*)BM;                      // [2*ECAP] static CSR (reuses BM region)
    int* NBR = OTH + 2 * ECAP;                // [2*ECAP]
    int* TMP = NBR + 2 * ECAP;                // [2*ECAP] A3 scratch
    char* meta = (char*)BM + (2u << 20);
    int* SEL   = (int*)meta;
    int* CNTS  = SEL  + NNODES;
    int* NST   = CNTS + NNODES;
    int* FIL   = NST  + NNODES;
    int* SC    = FIL  + NNODES;               // [16]
    float* out = (float*)d_out;

    // grid-parallel zero of the 2MB BM bitmap (graph-capture-safe plain kernel)
    hipLaunchKernelGGL(zeroBM, dim3(512), dim3(256), 0, stream, (int4*)BM);

    hipLaunchKernelGGL(phaseA, dim3(1), dim3(NT), 0, stream,
                       ei, E0, U, V, BM, NBR, OTH,
                       SEL, CNTS, NST, FIL, SC, TMP, out);

    hipLaunchKernelGGL(phaseB, dim3(NNODES), dim3(256), 0, stream,
                       x, W1, W2, B1, B2, NBR, SEL, CNTS, NST, FIL, SC, out);
}